// Round 8
// baseline (429.656 us; speedup 1.0000x reference)
//
#include <hip/hip_runtime.h>

// ---------------------------------------------------------------------------
// BeliefStateWrapper: gather(fi,bi) -> Linear(1024->512)+LeakyReLU ->
// Linear(512->64000) -> per-branch log_softmax NLL -> weighted mean (scalar).
//
// R16: gemm2 K-loop moved from 16x16x32 to 32x32x16 MFMA. Measured
// per-instruction costs: 16x16x32 = 4.85 cy/16kFLOP, 32x32x16 = 4.06
// (m119) -> MFMA pipe term of the serial-sum model (TCP 1024 + LDS 768 +
// MFMA 1240 cy/round) drops 1240 -> 1033. Same A/B/acc register budget
// (acc = 4 x f32x16 = 64 AGPR; frag 16+16+16 VGPR), same traffic, same
// 2x64KB LDS box, same 4 waves/SIMD. Epilogue split per 32-row block so
// live regs stay lc[16]+rs[16] = 32 (the R4 spill budget). Apack is
// re-laid-out for the 32x32 fragment (gemm1 pack epilogue re-derived,
// same chunk count/coalescing). Operand layouts follow the verified
// gfx950 family: A[l&31][(l>>5)*8+j], B[(l>>5)*8+j][l&31], C/D
// col=lane&31,row=(reg&3)+8*(reg>>2)+4*(lane>>5) (m74/m101).
// R15 gains kept (prep zeroes out; gemm1 reg-dbuf staging).
// ---------------------------------------------------------------------------

typedef __bf16 bf16x8 __attribute__((ext_vector_type(8)));
typedef __bf16 bf16x4 __attribute__((ext_vector_type(4)));
typedef float f32x4  __attribute__((ext_vector_type(4)));
typedef float f32x16 __attribute__((ext_vector_type(16)));

#define MFMA16(a, b, c) __builtin_amdgcn_mfma_f32_16x16x32_bf16(a, b, c, 0, 0, 0)
#define MFMA32(a, b, c) __builtin_amdgcn_mfma_f32_32x32x16_bf16(a, b, c, 0, 0, 0)

static constexpr int Bsz   = 2;
static constexpr int L     = 512;
static constexpr int D     = 512;
static constexpr int V     = 32000;
static constexpr int K1    = 2 * D;      // 1024
static constexpr int N1    = D;          // 512
static constexpr int K2    = D;          // 512
static constexpr int N2    = 2 * V;      // 64000
static constexpr int NSTRIP = N2 / 64;   // 1000 strips (500 per branch)

// Apack chunk base (bf16 elems) for (panel, ks, sub, bi2); chunk = 64 lanes
// x 8 bf16 = 512 elems = 1 KB.  Lane l holds
// A[panel*64 + bi2*32 + (l&31)][ks*32 + sub*16 + (l>>5)*8 .. +7]
// -- the 32x32x16 MFMA A-operand fragment.
__device__ __host__ inline size_t apack_chunk(int panel, int ks, int sub, int bi2) {
    return ((((size_t)panel * 16 + ks) * 2 + sub) * 2 + bi2) * 512;
}

// ---------------------------------------------------------------------------
// prep kernel: blocks [0, G1) do gather+cast (+labcol side-task, interleaved
// labcol[m*2+br] layout); blocks [G1, G1+128) transpose+cast w1 -> W1T.
// Block 0 thread 0 also zeroes the output accumulator.
// ---------------------------------------------------------------------------
__global__ void prep_kernel(const float* __restrict__ fwd,
                            const float* __restrict__ bwd,
                            const int* __restrict__ fi,
                            const int* __restrict__ bi,
                            const int* __restrict__ seq,
                            const float* __restrict__ w1,
                            __bf16* __restrict__ A1,
                            __bf16* __restrict__ W1T,
                            int* __restrict__ labcol,
                            float* __restrict__ out,
                            int N, int M, int Mpad, int G1) {
    __shared__ __align__(16) __bf16 tile[64][68];
    if ((int)blockIdx.x >= G1) {
        // ---- w1 transpose part: bid -> (bx in [0,8), by in [0,16))
        int bid = blockIdx.x - G1;
        int bx = bid & 7, by = bid >> 3;
        int t  = threadIdx.x;
        int tx = t & 15, ty = t >> 4;
        int n0 = bx * 64, k0 = by * 64;
        for (int i = 0; i < 4; i++) {
            int k = k0 + ty + 16 * i;
            float4 v = *(const float4*)(w1 + (size_t)k * N1 + n0 + tx * 4);
            tile[tx * 4 + 0][ty + 16 * i] = (__bf16)v.x;
            tile[tx * 4 + 1][ty + 16 * i] = (__bf16)v.y;
            tile[tx * 4 + 2][ty + 16 * i] = (__bf16)v.z;
            tile[tx * 4 + 3][ty + 16 * i] = (__bf16)v.w;
        }
        __syncthreads();
        for (int i = 0; i < 4; i++) {
            int n = n0 + ty + 16 * i;
            bf16x4 o;
            o[0] = tile[ty + 16 * i][tx * 4 + 0];
            o[1] = tile[ty + 16 * i][tx * 4 + 1];
            o[2] = tile[ty + 16 * i][tx * 4 + 2];
            o[3] = tile[ty + 16 * i][tx * 4 + 3];
            *(bf16x4*)(W1T + (size_t)n * K1 + k0 + tx * 4) = o;
        }
        return;
    }
    int t = blockIdx.x * 256 + threadIdx.x;          // one thread = 8 elems
    if (t == 0) *out = 0.0f;                          // replaces memset launch
    // side-task: label columns, interleaved labcol[m*2+br]
    if (t < Mpad * 2) {
        int m = t >> 1, br = t & 1;
        if (m >= M) labcol[m * 2 + br] = -1;
        else {
            int b = m / N, n = m - b * N;
            int tok = br ? seq[b * L + bi[n]] : seq[b * L + fi[n]];
            labcol[m * 2 + br] = br * V + tok;
        }
    }
    int total = Mpad * (K1 / 8);
    if (t >= total) return;
    int m  = t >> 7;              // / (1024/8)
    int c8 = (t & 127) * 8;
    bf16x8 out8;
    if (m < M) {
        int b = m / N;
        int n = m - b * N;
        const float* src;
        if (c8 < D) src = fwd + ((size_t)(b * L + fi[n])) * D + c8;
        else        src = bwd + ((size_t)(b * L + bi[n])) * D + (c8 - D);
        float4 v0 = *(const float4*)(src);
        float4 v1 = *(const float4*)(src + 4);
        out8[0] = (__bf16)v0.x; out8[1] = (__bf16)v0.y;
        out8[2] = (__bf16)v0.z; out8[3] = (__bf16)v0.w;
        out8[4] = (__bf16)v1.x; out8[5] = (__bf16)v1.y;
        out8[6] = (__bf16)v1.z; out8[7] = (__bf16)v1.w;
    } else {
        for (int j = 0; j < 8; j++) out8[j] = (__bf16)0.0f;
    }
    *(bf16x8*)(A1 + (size_t)m * K1 + c8) = out8;
}

// ---------------------------------------------------------------------------
// GEMM1: H = leaky_relu(A1 @ W1 + b1), emitted in Apack fragment-major
// layout (32x32x16 fragments).  128x128 tile, 4 waves (2x2), 16x16x32
// MFMA, BK=32, register-double-buffered staging (R15).  Epilogue
// round-trips C through LDS so the Apack stores are fully coalesced.
// ---------------------------------------------------------------------------
__global__ __launch_bounds__(256) void gemm1_kernel(
        const __bf16* __restrict__ A, const __bf16* __restrict__ Bt,
        const float* __restrict__ bias, __bf16* __restrict__ Apack, int K) {
    __shared__ __align__(16) __bf16 At[128][40];
    __shared__ __align__(16) __bf16 Bl[128][40];
    __shared__ __align__(16) __bf16 Cld[128][136];
    const int t = threadIdx.x;
    const int by = blockIdx.y, bx = blockIdx.x;
    const int m0 = by * 128, n0 = bx * 128;
    const int srow = t >> 2, schunk = (t & 3) * 8;
    const int wave = t >> 6, lane = t & 63;
    const int wrow = (wave >> 1) * 64, wcol = (wave & 1) * 64;
    const int q = lane >> 4, ln = lane & 15;

    // prologue: load k0 = 0 staging chunks into registers
    bf16x8 rA0 = *(const bf16x8*)(A  + (size_t)(m0 + srow)      * K + schunk);
    bf16x8 rA1 = *(const bf16x8*)(A  + (size_t)(m0 + srow + 64) * K + schunk);
    bf16x8 rB0 = *(const bf16x8*)(Bt + (size_t)(n0 + srow)      * K + schunk);
    bf16x8 rB1 = *(const bf16x8*)(Bt + (size_t)(n0 + srow + 64) * K + schunk);

    f32x4 acc[4][4] = {};
    for (int k0 = 0; k0 < K; k0 += 32) {
        __syncthreads();                       // prev iter's ds_reads done
        *(bf16x8*)&At[srow][schunk]      = rA0;
        *(bf16x8*)&At[srow + 64][schunk] = rA1;
        *(bf16x8*)&Bl[srow][schunk]      = rB0;
        *(bf16x8*)&Bl[srow + 64][schunk] = rB1;
        __syncthreads();
        if (k0 + 32 < K) {                     // prefetch next chunk
            int kn = k0 + 32 + schunk;
            rA0 = *(const bf16x8*)(A  + (size_t)(m0 + srow)      * K + kn);
            rA1 = *(const bf16x8*)(A  + (size_t)(m0 + srow + 64) * K + kn);
            rB0 = *(const bf16x8*)(Bt + (size_t)(n0 + srow)      * K + kn);
            rB1 = *(const bf16x8*)(Bt + (size_t)(n0 + srow + 64) * K + kn);
        }
        bf16x8 af[4], bfr[4];
        for (int i = 0; i < 4; i++) af[i]  = *(const bf16x8*)&At[wrow + i * 16 + ln][q * 8];
        for (int i = 0; i < 4; i++) bfr[i] = *(const bf16x8*)&Bl[wcol + i * 16 + ln][q * 8];
        for (int mi = 0; mi < 4; mi++)
            for (int ni = 0; ni < 4; ni++)
                acc[mi][ni] = MFMA16(af[mi], bfr[ni], acc[mi][ni]);
    }
    // bias + leaky -> LDS C tile
    for (int ni = 0; ni < 4; ni++) {
        int gcol = n0 + wcol + ni * 16 + ln;
        float bv = bias[gcol];
        for (int mi = 0; mi < 4; mi++)
            for (int r = 0; r < 4; r++) {
                float v = acc[mi][ni][r] + bv;
                v = v > 0.0f ? v : 0.01f * v;
                Cld[wrow + mi * 16 + q * 4 + r][wcol + ni * 16 + ln] = (__bf16)v;
            }
    }
    __syncthreads();
    // pack out (32x32x16 fragment layout): 32 chunks
    // c -> (pl = c>>4, ksl = (c>>2)&3, sub = (c>>1)&1, bi2 = c&1)
    // lane l writes row pl*64 + bi2*32 + (l&31),
    //               col ksl*32 + sub*16 + (l>>5)*8 .. +7
    for (int i = 0; i < 8; i++) {
        int c   = wave + 4 * i;
        int pl  = c >> 4, ksl = (c >> 2) & 3, sub = (c >> 1) & 1, bi2 = c & 1;
        int row = pl * 64 + bi2 * 32 + (lane & 31);
        int col = ksl * 32 + sub * 16 + (lane >> 5) * 8;
        bf16x8 v = *(const bf16x8*)&Cld[row][col];
        size_t base = apack_chunk(2 * by + pl, 4 * bx + ksl, sub, bi2);
        *(bf16x8*)(Apack + base + lane * 8) = v;
    }
}

// ---------------------------------------------------------------------------
// GEMM2 (persistent 64-col strip, 512 threads = 8 waves, 2 blocks/CU) --
// R4 resource box, 32x32x16 MFMA K-loop (128 MFMAs/panel @ 4.06 cy/16kFLOP
// vs 256 @ 4.85).  W2 strip staged once fp32->bf16 into fragment-major LDS
// "Bpack" (conflict-free b128; non-temporal loads protect Apack's L2
// residency).  A frags from L2 with one-k-step prefetch (R8 pattern).
// Epilogue per 32-row block (bi2) keeps live regs at lc[16]+rs[16] = 32,
// the R4 spill budget; order preserved: lc -> merged exp/label -> reduce.
// C/D mapping: col = lane&31, row = (reg&3) + 8*(reg>>2) + 4*(lane>>5).
// ---------------------------------------------------------------------------
__global__ __launch_bounds__(512, 4) void gemm2_kernel(
        const __bf16* __restrict__ Apack, const float* __restrict__ w2,
        const float* __restrict__ b2, const int* __restrict__ labcol,
        float* __restrict__ partial, float* __restrict__ lab, int Mpad) {
    __shared__ __align__(16) __bf16 Bp[64 * 512];   // 64 KB, fragment-major
    const int t = threadIdx.x;
    const int strip = blockIdx.x;
    const int c0 = strip * 64;
    const int branch = (c0 >= V) ? 1 : 0;

    // ---- stage W2 strip fp32 [512][64000] -> Bpack bf16 (32x32 B-frags)
    // frag (ks, sub, bj2): lane λ holds w2[ks*32+sub*16+(λ>>5)*8+j][c0+bj2*32+(λ&31)]
    {
        const int col = t & 63;
        const int bj2 = col >> 5, colh = col & 31;
        const int kb0 = (t >> 6) * 8;
        for (int r = 0; r < 8; r++) {
            int kb = kb0 + r * 64;
            int ks = kb >> 5, sub = (kb >> 4) & 1, ko = (kb >> 3) & 1;
            float v[8];
#pragma unroll
            for (int j = 0; j < 8; j++)
                v[j] = __builtin_nontemporal_load(w2 + (size_t)(kb + j) * N2 + c0 + col);
            bf16x8 o;
#pragma unroll
            for (int j = 0; j < 8; j++) o[j] = (__bf16)v[j];
            *(bf16x8*)&Bp[(size_t)((((ks * 2 + sub) * 2 + bj2) * 64) + ko * 32 + colh) * 8] = o;
        }
    }
    __syncthreads();

    const int wave = t >> 6, lane = t & 63;
    const int h = lane >> 5, cl = lane & 31;

    float bv2[2];
#pragma unroll
    for (int bj2 = 0; bj2 < 2; bj2++) bv2[bj2] = b2[c0 + bj2 * 32 + cl];

    // final-store decode: lane stores global row p*64 + lane
    const int rlt  = lane & 31;                   // row within 32-block
    const int regt = (rlt & 3) + 4 * (rlt >> 3);  // which acc reg holds it
    const int hnt  = (rlt >> 2) & 1;              // which lane-half holds it

    const int npanels = Mpad >> 6;
    for (int p = wave; p < npanels; p += 8) {
        const __bf16* base = Apack + apack_chunk(p, 0, 0, 0) + lane * 8;

        f32x16 acc[2][2] = {};
        bf16x8 afc[2][2], afn[2][2];
#pragma unroll
        for (int sub = 0; sub < 2; sub++)
#pragma unroll
            for (int bi2 = 0; bi2 < 2; bi2++)
                afc[sub][bi2] = *(const bf16x8*)(base + (size_t)(sub * 2 + bi2) * 512);
#pragma unroll 1
        for (int ks = 0; ks < 16; ks++) {
            if (ks < 15) {
#pragma unroll
                for (int sub = 0; sub < 2; sub++)
#pragma unroll
                    for (int bi2 = 0; bi2 < 2; bi2++)
                        afn[sub][bi2] = *(const bf16x8*)(base + (size_t)(((ks + 1) * 2 + sub) * 2 + bi2) * 512);
            }
            bf16x8 bfr[2][2];
#pragma unroll
            for (int sub = 0; sub < 2; sub++)
#pragma unroll
                for (int bj2 = 0; bj2 < 2; bj2++)
                    bfr[sub][bj2] = *(const bf16x8*)&Bp[(size_t)((ks * 2 + sub) * 2 + bj2) * 512 + lane * 8];
#pragma unroll
            for (int sub = 0; sub < 2; sub++)
#pragma unroll
                for (int bi2 = 0; bi2 < 2; bi2++)
#pragma unroll
                    for (int bj2 = 0; bj2 < 2; bj2++)
                        acc[bi2][bj2] = MFMA32(afc[sub][bi2], bfr[sub][bj2], acc[bi2][bj2]);
#pragma unroll
            for (int sub = 0; sub < 2; sub++)
#pragma unroll
                for (int bi2 = 0; bi2 < 2; bi2++)
                    afc[sub][bi2] = afn[sub][bi2];
        }

        // ---- epilogue, per 32-row block (R4 order within each block)
        float mine = 0.0f;
#pragma unroll
        for (int bi2 = 0; bi2 < 2; bi2++) {
            int lc16[16];
#pragma unroll
            for (int reg = 0; reg < 16; reg++)
                lc16[reg] = labcol[(p * 64 + bi2 * 32 + (reg & 3) + 8 * (reg >> 2) + 4 * h) * 2 + branch];

            float rs[16];
#pragma unroll
            for (int reg = 0; reg < 16; reg++) rs[reg] = 0.0f;

#pragma unroll
            for (int bj2 = 0; bj2 < 2; bj2++) {
                const int gcol = c0 + bj2 * 32 + cl;
                const float bv = bv2[bj2];
#pragma unroll
                for (int reg = 0; reg < 16; reg++) {
                    float v = acc[bi2][bj2][reg] + bv;
                    rs[reg] += __expf(v);
                    if (gcol == lc16[reg]) {
                        int gm = p * 64 + bi2 * 32 + (reg & 3) + 8 * (reg >> 2) + 4 * h;
                        lab[gm * 2 + branch] = v;
                    }
                }
            }
            // reduce over the 32 column-lanes (lane bits 0..4; stays in-half)
#pragma unroll
            for (int reg = 0; reg < 16; reg++) {
                float s = rs[reg];
                s += __shfl_xor(s, 1);
                s += __shfl_xor(s, 2);
                s += __shfl_xor(s, 4);
                s += __shfl_xor(s, 8);
                s += __shfl_xor(s, 16);
                rs[reg] = s;
            }
            // gather: lane l stores row p*64+l; its value lives in half hnt
            // at reg regt (valid in all 32 lanes of that half after reduce).
#pragma unroll
            for (int reg = 0; reg < 16; reg++) {
                float tv = __shfl(rs[reg], hnt * 32 + cl);
                if ((lane >> 5) == bi2 && regt == reg) mine = tv;
            }
        }
        partial[(size_t)strip * Mpad + p * 64 + lane] = mine;
    }
}

// ---------------------------------------------------------------------------
// Fused final: block per (64-row panel, branch). 4 waves split the branch's
// 500 strips (125 each), coalesced 256 B reads, LDS combine, then wave 0
// computes nll = log(sumexp) - lab, weights, reduces, atomicAdd into out.
// ---------------------------------------------------------------------------
__global__ __launch_bounds__(256) void final_kernel(
        const float* __restrict__ partial, const float* __restrict__ lab,
        float* __restrict__ out, int M, int Mpad) {
    __shared__ float red[4][64];
    const int br = blockIdx.x & 1;
    const int m0 = (blockIdx.x >> 1) * 64;
    const int wave = threadIdx.x >> 6, lane = threadIdx.x & 63;
    const int s0 = br * (NSTRIP / 2) + wave * (NSTRIP / 8);
    float s = 0.0f;
#pragma unroll 5
    for (int i = 0; i < NSTRIP / 8; i++)
        s += partial[(size_t)(s0 + i) * Mpad + m0 + lane];
    red[wave][lane] = s;
    __syncthreads();
    if (wave == 0) {
        float tot = red[0][lane] + red[1][lane] + red[2][lane] + red[3][lane];
        int m = m0 + lane;
        float acc = 0.0f;
        if (m < M)
            acc = (br ? 0.25f : 1.0f) * (logf(tot) - lab[m * 2 + br]);
        acc += __shfl_xor(acc, 32);
        acc += __shfl_xor(acc, 16);
        acc += __shfl_xor(acc, 8);
        acc += __shfl_xor(acc, 4);
        acc += __shfl_xor(acc, 2);
        acc += __shfl_xor(acc, 1);
        if (lane == 0) atomicAdd(out, acc / (float)(2 * M));
    }
}

// ---------------------------------------------------------------------------
extern "C" void kernel_launch(void* const* d_in, const int* in_sizes, int n_in,
                              void* d_out, int out_size, void* d_ws, size_t ws_size,
                              hipStream_t stream) {
    const float* fwd = (const float*)d_in[0];
    const float* bwd = (const float*)d_in[1];
    const int*   seq = (const int*)d_in[2];
    const int*   fi  = (const int*)d_in[3];
    const int*   bi  = (const int*)d_in[4];
    const float* w1  = (const float*)d_in[5];
    const float* b1  = (const float*)d_in[6];
    const float* w2  = (const float*)d_in[7];
    const float* b2  = (const float*)d_in[8];
    float* out = (float*)d_out;

    const int N    = in_sizes[3];              // 1303
    const int M    = Bsz * N;                  // 2606
    const int Mpad = ((M + 255) / 256) * 256;  // 2816

    // workspace layout (16B-aligned slices)
    char* ws = (char*)d_ws;
    __bf16* A1    = (__bf16*)(ws);                                   // Mpad*1024
    __bf16* W1T   = (__bf16*)(ws + (size_t)Mpad * K1 * 2);           // 512*1024
    __bf16* Apack = (__bf16*)((char*)W1T + (size_t)N1 * K1 * 2);     // Mpad*512
    float*  partial = (float*)((char*)Apack + (size_t)Mpad * N1 * 2);// NSTRIP*Mpad
    float*  lab     = (float*)((char*)partial + (size_t)NSTRIP * Mpad * 4); // Mpad*2
    int*    labcol  = (int*)((char*)lab + (size_t)Mpad * 2 * 4);     // Mpad*2

    // 1. fused prep: gather+cast (+labcol interleaved), w1 transpose,
    //    and out zeroing (no separate memset dispatch)
    {
        int G1 = Mpad * (K1 / 8) / 256;        // gather blocks
        prep_kernel<<<G1 + 128, 256, 0, stream>>>(
            fwd, bwd, fi, bi, seq, w1, A1, W1T, labcol, out, N, M, Mpad, G1);
    }
    // 2. GEMM1 -> Apack (32x32-fragment-major H), register-dbuf staging
    gemm1_kernel<<<dim3(N1 / 128, Mpad / 128), 256, 0, stream>>>(A1, W1T, b1, Apack, K1);
    // 3. GEMM2 persistent strips (32x32x16 MFMA) -> partial rowsums + labels
    gemm2_kernel<<<NSTRIP, 512, 0, stream>>>(Apack, w2, b2, labcol, partial, lab, Mpad);
    // 4. fused final: strip-reduce + NLL + weighted mean -> out
    final_kernel<<<(Mpad / 64) * 2, 256, 0, stream>>>(partial, lab, out, M, Mpad);
}

// Round 9
// 389.465 us; speedup vs baseline: 1.1032x; 1.1032x over previous
//
#include <hip/hip_runtime.h>

// ---------------------------------------------------------------------------
// BeliefStateWrapper: gather(fi,bi) -> Linear(1024->512)+LeakyReLU ->
// Linear(512->64000) -> per-branch log_softmax NLL -> weighted mean (scalar).
//
// R17 = R15 (394.1us anchor) + cross-panel A-prefetch in gemm2 (T14
// issue-early/wait-late). R16 post-mortem: 32x32x16 MFMA busy-time equal
// to 16x16x32 (4-deep acc independence can't reach the 8.07cy ubench) and
// 2.4x epilogue shfl cost -> +42us; fully reverted.
// gemm2 change vs R8-verbatim K-loop, surgical: at ks==15 the afn prefetch
// slot (otherwise idle) loads NEXT panel's chunk 0; the ks=15 afc=afn copy
// is skipped (would force the vmcnt wait) and moved to AFTER the epilogue,
// so the ~1400cy epilogue hides the load's L2/TCP latency. Removes the
// 200-700cy panel-start A-load stall. Live-range cost: afn stays live
// through the epilogue (+16 VGPR on a ~46-reg epilogue live set) -- go/no-go
// signal is VGPR_Count staying 64 (the 128-unified-reg / 4-waves-per-SIMD
// bracket).
// R15 kept: prep zeroes out (no memset dispatch); gemm1 reg-dbuf staging;
// R4 epilogue order (lc -> merged exp/label -> reduce; do not reorder).
// ---------------------------------------------------------------------------

typedef __bf16 bf16x8 __attribute__((ext_vector_type(8)));
typedef __bf16 bf16x4 __attribute__((ext_vector_type(4)));
typedef float f32x4  __attribute__((ext_vector_type(4)));

#define MFMA16(a, b, c) __builtin_amdgcn_mfma_f32_16x16x32_bf16(a, b, c, 0, 0, 0)

static constexpr int Bsz   = 2;
static constexpr int L     = 512;
static constexpr int D     = 512;
static constexpr int V     = 32000;
static constexpr int K1    = 2 * D;      // 1024
static constexpr int N1    = D;          // 512
static constexpr int K2    = D;          // 512
static constexpr int N2    = 2 * V;      // 64000
static constexpr int NSTRIP = N2 / 64;   // 1000 strips (500 per branch)

// Apack chunk base (bf16 elems) for (panel, ks, mi); chunk = 64 lanes x 8
// bf16 = 512 elems = 1 KB. Lane l holds A[panel*64+mi*16+(l&15)]
// [ks*32+(l>>4)*8 .. +7].
__device__ __host__ inline size_t apack_chunk(int panel, int ks, int mi) {
    return (((size_t)panel * 16 + ks) * 4 + mi) * 512;
}

// ---------------------------------------------------------------------------
// prep kernel: blocks [0, G1) do gather+cast (+labcol side-task, interleaved
// labcol[m*2+br] layout); blocks [G1, G1+128) transpose+cast w1 -> W1T.
// Block 0 thread 0 also zeroes the output accumulator.
// ---------------------------------------------------------------------------
__global__ void prep_kernel(const float* __restrict__ fwd,
                            const float* __restrict__ bwd,
                            const int* __restrict__ fi,
                            const int* __restrict__ bi,
                            const int* __restrict__ seq,
                            const float* __restrict__ w1,
                            __bf16* __restrict__ A1,
                            __bf16* __restrict__ W1T,
                            int* __restrict__ labcol,
                            float* __restrict__ out,
                            int N, int M, int Mpad, int G1) {
    __shared__ __align__(16) __bf16 tile[64][68];
    if ((int)blockIdx.x >= G1) {
        // ---- w1 transpose part: bid -> (bx in [0,8), by in [0,16))
        int bid = blockIdx.x - G1;
        int bx = bid & 7, by = bid >> 3;
        int t  = threadIdx.x;
        int tx = t & 15, ty = t >> 4;
        int n0 = bx * 64, k0 = by * 64;
        for (int i = 0; i < 4; i++) {
            int k = k0 + ty + 16 * i;
            float4 v = *(const float4*)(w1 + (size_t)k * N1 + n0 + tx * 4);
            tile[tx * 4 + 0][ty + 16 * i] = (__bf16)v.x;
            tile[tx * 4 + 1][ty + 16 * i] = (__bf16)v.y;
            tile[tx * 4 + 2][ty + 16 * i] = (__bf16)v.z;
            tile[tx * 4 + 3][ty + 16 * i] = (__bf16)v.w;
        }
        __syncthreads();
        for (int i = 0; i < 4; i++) {
            int n = n0 + ty + 16 * i;
            bf16x4 o;
            o[0] = tile[ty + 16 * i][tx * 4 + 0];
            o[1] = tile[ty + 16 * i][tx * 4 + 1];
            o[2] = tile[ty + 16 * i][tx * 4 + 2];
            o[3] = tile[ty + 16 * i][tx * 4 + 3];
            *(bf16x4*)(W1T + (size_t)n * K1 + k0 + tx * 4) = o;
        }
        return;
    }
    int t = blockIdx.x * 256 + threadIdx.x;          // one thread = 8 elems
    if (t == 0) *out = 0.0f;                          // replaces memset launch
    // side-task: label columns, interleaved labcol[m*2+br]
    if (t < Mpad * 2) {
        int m = t >> 1, br = t & 1;
        if (m >= M) labcol[m * 2 + br] = -1;
        else {
            int b = m / N, n = m - b * N;
            int tok = br ? seq[b * L + bi[n]] : seq[b * L + fi[n]];
            labcol[m * 2 + br] = br * V + tok;
        }
    }
    int total = Mpad * (K1 / 8);
    if (t >= total) return;
    int m  = t >> 7;              // / (1024/8)
    int c8 = (t & 127) * 8;
    bf16x8 out8;
    if (m < M) {
        int b = m / N;
        int n = m - b * N;
        const float* src;
        if (c8 < D) src = fwd + ((size_t)(b * L + fi[n])) * D + c8;
        else        src = bwd + ((size_t)(b * L + bi[n])) * D + (c8 - D);
        float4 v0 = *(const float4*)(src);
        float4 v1 = *(const float4*)(src + 4);
        out8[0] = (__bf16)v0.x; out8[1] = (__bf16)v0.y;
        out8[2] = (__bf16)v0.z; out8[3] = (__bf16)v0.w;
        out8[4] = (__bf16)v1.x; out8[5] = (__bf16)v1.y;
        out8[6] = (__bf16)v1.z; out8[7] = (__bf16)v1.w;
    } else {
        for (int j = 0; j < 8; j++) out8[j] = (__bf16)0.0f;
    }
    *(bf16x8*)(A1 + (size_t)m * K1 + c8) = out8;
}

// ---------------------------------------------------------------------------
// GEMM1: H = leaky_relu(A1 @ W1 + b1), emitted in Apack fragment-major
// layout.  128x128 tile, 4 waves (2x2), 16x16x32 MFMA, BK=32,
// register-double-buffered staging (R15).  Epilogue round-trips C through
// LDS so the Apack stores are fully coalesced.
// ---------------------------------------------------------------------------
__global__ __launch_bounds__(256) void gemm1_kernel(
        const __bf16* __restrict__ A, const __bf16* __restrict__ Bt,
        const float* __restrict__ bias, __bf16* __restrict__ Apack, int K) {
    __shared__ __align__(16) __bf16 At[128][40];
    __shared__ __align__(16) __bf16 Bl[128][40];
    __shared__ __align__(16) __bf16 Cld[128][136];
    const int t = threadIdx.x;
    const int by = blockIdx.y, bx = blockIdx.x;
    const int m0 = by * 128, n0 = bx * 128;
    const int srow = t >> 2, schunk = (t & 3) * 8;
    const int wave = t >> 6, lane = t & 63;
    const int wrow = (wave >> 1) * 64, wcol = (wave & 1) * 64;
    const int q = lane >> 4, ln = lane & 15;

    // prologue: load k0 = 0 staging chunks into registers
    bf16x8 rA0 = *(const bf16x8*)(A  + (size_t)(m0 + srow)      * K + schunk);
    bf16x8 rA1 = *(const bf16x8*)(A  + (size_t)(m0 + srow + 64) * K + schunk);
    bf16x8 rB0 = *(const bf16x8*)(Bt + (size_t)(n0 + srow)      * K + schunk);
    bf16x8 rB1 = *(const bf16x8*)(Bt + (size_t)(n0 + srow + 64) * K + schunk);

    f32x4 acc[4][4] = {};
    for (int k0 = 0; k0 < K; k0 += 32) {
        __syncthreads();                       // prev iter's ds_reads done
        *(bf16x8*)&At[srow][schunk]      = rA0;
        *(bf16x8*)&At[srow + 64][schunk] = rA1;
        *(bf16x8*)&Bl[srow][schunk]      = rB0;
        *(bf16x8*)&Bl[srow + 64][schunk] = rB1;
        __syncthreads();
        if (k0 + 32 < K) {                     // prefetch next chunk
            int kn = k0 + 32 + schunk;
            rA0 = *(const bf16x8*)(A  + (size_t)(m0 + srow)      * K + kn);
            rA1 = *(const bf16x8*)(A  + (size_t)(m0 + srow + 64) * K + kn);
            rB0 = *(const bf16x8*)(Bt + (size_t)(n0 + srow)      * K + kn);
            rB1 = *(const bf16x8*)(Bt + (size_t)(n0 + srow + 64) * K + kn);
        }
        bf16x8 af[4], bfr[4];
        for (int i = 0; i < 4; i++) af[i]  = *(const bf16x8*)&At[wrow + i * 16 + ln][q * 8];
        for (int i = 0; i < 4; i++) bfr[i] = *(const bf16x8*)&Bl[wcol + i * 16 + ln][q * 8];
        for (int mi = 0; mi < 4; mi++)
            for (int ni = 0; ni < 4; ni++)
                acc[mi][ni] = MFMA16(af[mi], bfr[ni], acc[mi][ni]);
    }
    // bias + leaky -> LDS C tile
    for (int ni = 0; ni < 4; ni++) {
        int gcol = n0 + wcol + ni * 16 + ln;
        float bv = bias[gcol];
        for (int mi = 0; mi < 4; mi++)
            for (int r = 0; r < 4; r++) {
                float v = acc[mi][ni][r] + bv;
                v = v > 0.0f ? v : 0.01f * v;
                Cld[wrow + mi * 16 + q * 4 + r][wcol + ni * 16 + ln] = (__bf16)v;
            }
    }
    __syncthreads();
    // pack out: 32 chunks (pl 0..1, ksl 0..3, mi 0..3), wave w -> c = w+4i
    for (int i = 0; i < 8; i++) {
        int c   = wave + 4 * i;
        int pl  = c >> 4, ksl = (c >> 2) & 3, mi = c & 3;
        int row = pl * 64 + mi * 16 + (lane & 15);
        int col = ksl * 32 + (lane >> 4) * 8;
        bf16x8 v = *(const bf16x8*)&Cld[row][col];
        size_t base = apack_chunk(2 * by + pl, 4 * bx + ksl, mi);
        *(bf16x8*)(Apack + base + lane * 8) = v;
    }
}

// ---------------------------------------------------------------------------
// GEMM2 (persistent 64-col strip, 512 threads = 8 waves, 2 blocks/CU) --
// R4/R8 schedule + R17 cross-panel A-prefetch (spill-free at the
// 64-arch-VGPR cap; do not reorder the epilogue: lc loads -> merged
// label/exp loop -> reduce).  W2 strip staged once fp32->bf16 into
// fragment-major LDS "Bpack" (conflict-free b128; non-temporal loads
// protect Apack's L2 residency).  A frags from L2 with one-k-step
// prefetch; at ks==15 the prefetch slot loads NEXT panel's chunk 0, whose
// vmcnt wait is deferred to AFTER the epilogue (the copy at loop bottom).
// ---------------------------------------------------------------------------
__global__ __launch_bounds__(512, 4) void gemm2_kernel(
        const __bf16* __restrict__ Apack, const float* __restrict__ w2,
        const float* __restrict__ b2, const int* __restrict__ labcol,
        float* __restrict__ partial, float* __restrict__ lab, int Mpad) {
    __shared__ __align__(16) __bf16 Bp[64 * 512];   // 64 KB, fragment-major
    const int t = threadIdx.x;
    const int strip = blockIdx.x;
    const int c0 = strip * 64;
    const int branch = (c0 >= V) ? 1 : 0;

    // ---- stage W2 strip fp32 [512][64000] -> Bpack bf16
    {
        const int col = t & 63;
        const int ni = col >> 4, lncol = col & 15;
        const int kb0 = (t >> 6) * 8;
        for (int r = 0; r < 8; r++) {
            int kb = kb0 + r * 64;
            int ks = kb >> 5, qk = (kb >> 3) & 3;
            float v[8];
#pragma unroll
            for (int j = 0; j < 8; j++)
                v[j] = __builtin_nontemporal_load(w2 + (size_t)(kb + j) * N2 + c0 + col);
            bf16x8 o;
#pragma unroll
            for (int j = 0; j < 8; j++) o[j] = (__bf16)v[j];
            *(bf16x8*)&Bp[(size_t)(((ks * 4 + ni) * 64 + qk * 16 + lncol)) * 8] = o;
        }
    }
    __syncthreads();

    const int wave = t >> 6, lane = t & 63;
    const int q = lane >> 4, ln = lane & 15;

    float bvn[4];
#pragma unroll
    for (int ni = 0; ni < 4; ni++) bvn[ni] = b2[c0 + ni * 16 + ln];

    const int npanels = Mpad >> 6;

    // prologue: first panel's chunk-0 A fragments
    bf16x8 afc[4], afn[4];
    {
        const __bf16* fb = Apack + apack_chunk(wave, 0, 0) + lane * 8;
#pragma unroll
        for (int mi = 0; mi < 4; mi++)
            afc[mi] = *(const bf16x8*)(fb + mi * 512);
    }

    for (int p = wave; p < npanels; p += 8) {
        const __bf16* base = Apack + apack_chunk(p, 0, 0) + lane * 8;
        const int pn = (p + 8 < npanels) ? (p + 8) : wave;   // last: dummy (L1-hot)
        const __bf16* nbase = Apack + apack_chunk(pn, 0, 0) + lane * 8;

        f32x4 acc[4][4] = {};
#pragma unroll 1
        for (int ks = 0; ks < 16; ks++) {
            // prefetch: next k-step, or NEXT PANEL's chunk 0 at ks==15
            const __bf16* pf = (ks < 15) ? (base + (size_t)(ks + 1) * 2048) : nbase;
#pragma unroll
            for (int mi = 0; mi < 4; mi++)
                afn[mi] = *(const bf16x8*)(pf + mi * 512);
            bf16x8 bf[4];
#pragma unroll
            for (int ni = 0; ni < 4; ni++)
                bf[ni] = *(const bf16x8*)&Bp[(size_t)(ks * 4 + ni) * 512 + lane * 8];
#pragma unroll
            for (int mi = 0; mi < 4; mi++)
#pragma unroll
                for (int ni = 0; ni < 4; ni++)
                    acc[mi][ni] = MFMA16(afc[mi], bf[ni], acc[mi][ni]);
            if (ks < 15) {
#pragma unroll
                for (int mi = 0; mi < 4; mi++) afc[mi] = afn[mi];
            }
            // ks==15: NO copy -- the next-panel loads stay in flight through
            // the epilogue (their vmcnt wait is at the loop-bottom copy).
        }

        // ---- epilogue for this panel (R4 order)
        int lc[4][4];
#pragma unroll
        for (int mi = 0; mi < 4; mi++)
#pragma unroll
            for (int r = 0; r < 4; r++)
                lc[mi][r] = labcol[(p * 64 + mi * 16 + q * 4 + r) * 2 + branch];

        float rowsum[4][4];
#pragma unroll
        for (int mi = 0; mi < 4; mi++)
#pragma unroll
            for (int r = 0; r < 4; r++) rowsum[mi][r] = 0.0f;

#pragma unroll
        for (int ni = 0; ni < 4; ni++) {
            const int gcol = c0 + ni * 16 + ln;
            const float bv = bvn[ni];
#pragma unroll
            for (int mi = 0; mi < 4; mi++)
#pragma unroll
                for (int r = 0; r < 4; r++) {
                    float v = acc[mi][ni][r] + bv;
                    rowsum[mi][r] += __expf(v);
                    if (gcol == lc[mi][r]) {
                        int gm = p * 64 + mi * 16 + q * 4 + r;
                        lab[gm * 2 + branch] = v;
                    }
                }
        }
        // reduce over the 16 column-lanes (lane bits 0..3)
#pragma unroll
        for (int mi = 0; mi < 4; mi++)
#pragma unroll
            for (int r = 0; r < 4; r++) {
                float s = rowsum[mi][r];
                s += __shfl_xor(s, 1);
                s += __shfl_xor(s, 2);
                s += __shfl_xor(s, 4);
                s += __shfl_xor(s, 8);
                rowsum[mi][r] = s;
            }
        // per-lane row gather: lane l wants row l = mi*16 + q*4 + r; value
        // lives in lanes with q-src = (l>>2)&3 at register rowsum[l>>4][l&3].
        float mine = 0.0f;
        const int srcl = ((lane >> 2) & 3) * 16;
#pragma unroll
        for (int mi2 = 0; mi2 < 4; mi2++)
#pragma unroll
            for (int r2 = 0; r2 < 4; r2++) {
                float tv = __shfl(rowsum[mi2][r2], srcl);
                if ((lane >> 4) == mi2 && (lane & 3) == r2) mine = tv;
            }
        partial[(size_t)strip * Mpad + p * 64 + lane] = mine;

        // consume the cross-panel prefetch (vmcnt wait lands HERE, after the
        // epilogue hid the load latency)
#pragma unroll
        for (int mi = 0; mi < 4; mi++) afc[mi] = afn[mi];
    }
}

// ---------------------------------------------------------------------------
// Fused final: block per (64-row panel, branch). 4 waves split the branch's
// 500 strips (125 each), coalesced 256 B reads, LDS combine, then wave 0
// computes nll = log(sumexp) - lab, weights, reduces, atomicAdd into out.
// ---------------------------------------------------------------------------
__global__ __launch_bounds__(256) void final_kernel(
        const float* __restrict__ partial, const float* __restrict__ lab,
        float* __restrict__ out, int M, int Mpad) {
    __shared__ float red[4][64];
    const int br = blockIdx.x & 1;
    const int m0 = (blockIdx.x >> 1) * 64;
    const int wave = threadIdx.x >> 6, lane = threadIdx.x & 63;
    const int s0 = br * (NSTRIP / 2) + wave * (NSTRIP / 8);
    float s = 0.0f;
#pragma unroll 5
    for (int i = 0; i < NSTRIP / 8; i++)
        s += partial[(size_t)(s0 + i) * Mpad + m0 + lane];
    red[wave][lane] = s;
    __syncthreads();
    if (wave == 0) {
        float tot = red[0][lane] + red[1][lane] + red[2][lane] + red[3][lane];
        int m = m0 + lane;
        float acc = 0.0f;
        if (m < M)
            acc = (br ? 0.25f : 1.0f) * (logf(tot) - lab[m * 2 + br]);
        acc += __shfl_xor(acc, 32);
        acc += __shfl_xor(acc, 16);
        acc += __shfl_xor(acc, 8);
        acc += __shfl_xor(acc, 4);
        acc += __shfl_xor(acc, 2);
        acc += __shfl_xor(acc, 1);
        if (lane == 0) atomicAdd(out, acc / (float)(2 * M));
    }
}

// ---------------------------------------------------------------------------
extern "C" void kernel_launch(void* const* d_in, const int* in_sizes, int n_in,
                              void* d_out, int out_size, void* d_ws, size_t ws_size,
                              hipStream_t stream) {
    const float* fwd = (const float*)d_in[0];
    const float* bwd = (const float*)d_in[1];
    const int*   seq = (const int*)d_in[2];
    const int*   fi  = (const int*)d_in[3];
    const int*   bi  = (const int*)d_in[4];
    const float* w1  = (const float*)d_in[5];
    const float* b1  = (const float*)d_in[6];
    const float* w2  = (const float*)d_in[7];
    const float* b2  = (const float*)d_in[8];
    float* out = (float*)d_out;

    const int N    = in_sizes[3];              // 1303
    const int M    = Bsz * N;                  // 2606
    const int Mpad = ((M + 255) / 256) * 256;  // 2816

    // workspace layout (16B-aligned slices)
    char* ws = (char*)d_ws;
    __bf16* A1    = (__bf16*)(ws);                                   // Mpad*1024
    __bf16* W1T   = (__bf16*)(ws + (size_t)Mpad * K1 * 2);           // 512*1024
    __bf16* Apack = (__bf16*)((char*)W1T + (size_t)N1 * K1 * 2);     // Mpad*512
    float*  partial = (float*)((char*)Apack + (size_t)Mpad * N1 * 2);// NSTRIP*Mpad
    float*  lab     = (float*)((char*)partial + (size_t)NSTRIP * Mpad * 4); // Mpad*2
    int*    labcol  = (int*)((char*)lab + (size_t)Mpad * 2 * 4);     // Mpad*2

    // 1. fused prep: gather+cast (+labcol interleaved), w1 transpose,
    //    and out zeroing (no separate memset dispatch)
    {
        int G1 = Mpad * (K1 / 8) / 256;        // gather blocks
        prep_kernel<<<G1 + 128, 256, 0, stream>>>(
            fwd, bwd, fi, bi, seq, w1, A1, W1T, labcol, out, N, M, Mpad, G1);
    }
    // 2. GEMM1 -> Apack (fragment-major H), register-dbuf staging
    gemm1_kernel<<<dim3(N1 / 128, Mpad / 128), 256, 0, stream>>>(A1, W1T, b1, Apack, K1);
    // 3. GEMM2 persistent strips (cross-panel A-prefetch) -> partials + labels
    gemm2_kernel<<<NSTRIP, 512, 0, stream>>>(Apack, w2, b2, labcol, partial, lab, Mpad);
    // 4. fused final: strip-reduce + NLL + weighted mean -> out
    final_kernel<<<(Mpad / 64) * 2, 256, 0, stream>>>(partial, lab, out, M, Mpad);
}